// Round 1
// baseline (1073.666 us; speedup 1.0000x reference)
//
#include <hip/hip_runtime.h>

#define N_NODES 100000
#define N_EDGES 1000000
#define IN_CH   128
#define OUT_CH  128
#define T_DIM   64
#define K_TOT   320   // 128 (x) + 128 (agg_x) + 64 (agg_t)

// ---------------------------------------------------------------------------
// Prep: build k-major weight matrix Gt[k][o] (k = 0..319) and bias2 = WTb+Tb
// ---------------------------------------------------------------------------
__global__ void prep_kernel(const float* __restrict__ WSw,
                            const float* __restrict__ WTw,
                            const float* __restrict__ Tw,
                            const float* __restrict__ WTb,
                            const float* __restrict__ Tb,
                            float* __restrict__ Gt,
                            float* __restrict__ bias2) {
    int idx = blockIdx.x * 256 + threadIdx.x;
    if (idx < K_TOT * 128) {
        int k = idx >> 7;
        int o = idx & 127;
        float v;
        if (k < 128)       v = WSw[o * 128 + k];
        else if (k < 256)  v = WTw[o * 128 + (k - 128)];
        else               v = Tw[o * 64 + (k - 256)];
        Gt[k * 128 + o] = v;
    }
    if (idx < 128) bias2[idx] = WTb[idx] + Tb[idx];
}

// ---------------------------------------------------------------------------
// Scatter: one wave (64 lanes) per edge.
//   agg_x[row] += x[col]            (128 floats, 2 per lane)
//   agg_t[row] += tf[e]             (64 floats, 1 per lane)
//   deg[row]   += 1                 (lane 0)
// ---------------------------------------------------------------------------
__global__ __launch_bounds__(256) void scatter_kernel(
        const float* __restrict__ x,
        const int*   __restrict__ ei,
        const float* __restrict__ tf,
        float* __restrict__ aggx,
        float* __restrict__ aggt,
        float* __restrict__ deg) {
    int wid  = threadIdx.x >> 6;
    int lane = threadIdx.x & 63;
    int e = blockIdx.x * 4 + wid;
    if (e >= N_EDGES) return;

    int row = ei[e];
    int col = ei[N_EDGES + e];

    size_t xb = (size_t)col * 128;
    float x0 = x[xb + lane];
    float x1 = x[xb + 64 + lane];
    float tv = tf[(size_t)e * 64 + lane];

    size_t ab = (size_t)row * 128;
    unsafeAtomicAdd(&aggx[ab + lane], x0);
    unsafeAtomicAdd(&aggx[ab + 64 + lane], x1);
    unsafeAtomicAdd(&aggt[(size_t)row * 64 + lane], tv);
    if (lane == 0) unsafeAtomicAdd(&deg[row], 1.0f);
}

// ---------------------------------------------------------------------------
// Node transform: out = relu([x | agg_x | agg_t] @ Gt + WSb + deg*bias2)
// Tiled SGEMM: 64 nodes x 128 outputs per block (256 threads),
// each thread computes 4 nodes x 8 outputs.
// NOTE: aggx aliases out (in-place) — deliberately NOT __restrict__.
// ---------------------------------------------------------------------------
__global__ __launch_bounds__(256) void gemm_kernel(
        const float* __restrict__ x,
        const float* aggx,
        const float* __restrict__ aggt,
        const float* __restrict__ Gt,
        const float* __restrict__ WSb,
        const float* __restrict__ bias2,
        const float* __restrict__ deg,
        float* out) {
    __shared__ float As[32][64];    // [kk][node]
    __shared__ float Bs[32][128];   // [kk][out]

    int tid = threadIdx.x;
    int tx = tid & 15;          // node group 0..15
    int ty = tid >> 4;          // out group  0..15
    int row0 = blockIdx.x * 64;

    float acc[4][8];
#pragma unroll
    for (int i = 0; i < 4; ++i)
#pragma unroll
        for (int j = 0; j < 8; ++j) acc[i][j] = 0.0f;

    int nn = tid >> 2;   // 0..63 : node for A staging
    int kq = tid & 3;    // 0..3  : 8-wide k slice for A staging
    int kr = tid >> 5;   // 0..7  : k row for B staging
    int o4 = (tid & 31) * 4;

    for (int c = 0; c < 10; ++c) {
        int kbase = c * 32;
        const float* src;
        int ld, koff;
        if (c < 4)      { src = x;    ld = 128; koff = kbase; }
        else if (c < 8) { src = aggx; ld = 128; koff = kbase - 128; }
        else            { src = aggt; ld = 64;  koff = kbase - 256; }

        int n = row0 + nn;
        float4 va = make_float4(0.f, 0.f, 0.f, 0.f);
        float4 vb = va;
        if (n < N_NODES) {
            const float* p = src + (size_t)n * ld + koff + kq * 8;
            va = *(const float4*)p;
            vb = *(const float4*)(p + 4);
        }

        __syncthreads();   // protect previous iteration's LDS reads

        int k0 = kq * 8;
        As[k0 + 0][nn] = va.x; As[k0 + 1][nn] = va.y;
        As[k0 + 2][nn] = va.z; As[k0 + 3][nn] = va.w;
        As[k0 + 4][nn] = vb.x; As[k0 + 5][nn] = vb.y;
        As[k0 + 6][nn] = vb.z; As[k0 + 7][nn] = vb.w;

#pragma unroll
        for (int r = 0; r < 4; ++r) {
            int kk = kr + r * 8;
            float4 b = *(const float4*)&Gt[(size_t)(kbase + kk) * 128 + o4];
            *(float4*)&Bs[kk][o4] = b;
        }

        __syncthreads();

#pragma unroll 8
        for (int kk = 0; kk < 32; ++kk) {
            float4 a4 = *(const float4*)&As[kk][tx * 4];
            float4 b0 = *(const float4*)&Bs[kk][ty * 8];
            float4 b1 = *(const float4*)&Bs[kk][ty * 8 + 4];
            float av[4] = {a4.x, a4.y, a4.z, a4.w};
            float bv[8] = {b0.x, b0.y, b0.z, b0.w, b1.x, b1.y, b1.z, b1.w};
#pragma unroll
            for (int i = 0; i < 4; ++i)
#pragma unroll
                for (int j = 0; j < 8; ++j)
                    acc[i][j] += av[i] * bv[j];
        }
    }

    // Epilogue: bias + deg*bias2 + ReLU. Safe to store in-place over aggx:
    // all global reads of this block's aggx rows happened during staging.
#pragma unroll
    for (int i = 0; i < 4; ++i) {
        int n = row0 + tx * 4 + i;
        if (n >= N_NODES) continue;
        float d = deg[n];
        float4 r0, r1;
        {
            int o = ty * 8;
            r0.x = fmaxf(acc[i][0] + WSb[o + 0] + d * bias2[o + 0], 0.f);
            r0.y = fmaxf(acc[i][1] + WSb[o + 1] + d * bias2[o + 1], 0.f);
            r0.z = fmaxf(acc[i][2] + WSb[o + 2] + d * bias2[o + 2], 0.f);
            r0.w = fmaxf(acc[i][3] + WSb[o + 3] + d * bias2[o + 3], 0.f);
            r1.x = fmaxf(acc[i][4] + WSb[o + 4] + d * bias2[o + 4], 0.f);
            r1.y = fmaxf(acc[i][5] + WSb[o + 5] + d * bias2[o + 5], 0.f);
            r1.z = fmaxf(acc[i][6] + WSb[o + 6] + d * bias2[o + 6], 0.f);
            r1.w = fmaxf(acc[i][7] + WSb[o + 7] + d * bias2[o + 7], 0.f);
        }
        float* po = out + (size_t)n * 128 + ty * 8;
        *(float4*)po = r0;
        *(float4*)(po + 4) = r1;
    }
}

// ---------------------------------------------------------------------------
extern "C" void kernel_launch(void* const* d_in, const int* in_sizes, int n_in,
                              void* d_out, int out_size, void* d_ws, size_t ws_size,
                              hipStream_t stream) {
    const float* x   = (const float*)d_in[0];
    const int*   ei  = (const int*)d_in[1];
    const float* tf  = (const float*)d_in[2];
    const float* WSw = (const float*)d_in[3];
    const float* WSb = (const float*)d_in[4];
    const float* WTw = (const float*)d_in[5];
    const float* WTb = (const float*)d_in[6];
    const float* Tw  = (const float*)d_in[7];
    const float* Tb  = (const float*)d_in[8];
    float* out = (float*)d_out;

    // Workspace layout (all fp32):
    //   agg_t : N_NODES*64
    //   deg   : N_NODES
    //   Gt    : 320*128
    //   bias2 : 128
    float* aggt  = (float*)d_ws;
    float* deg   = aggt + (size_t)N_NODES * 64;
    float* Gt    = deg + N_NODES;
    float* bias2 = Gt + (size_t)K_TOT * 128;
    float* aggx  = out;   // reuse output buffer as agg_x accumulator

    hipMemsetAsync(aggx, 0, (size_t)N_NODES * 128 * sizeof(float), stream);
    hipMemsetAsync(d_ws, 0, ((size_t)N_NODES * 64 + N_NODES) * sizeof(float), stream);

    prep_kernel<<<(K_TOT * 128 + 255) / 256, 256, 0, stream>>>(
        WSw, WTw, Tw, WTb, Tb, Gt, bias2);

    scatter_kernel<<<(N_EDGES + 3) / 4, 256, 0, stream>>>(
        x, ei, tf, aggx, aggt, deg);

    gemm_kernel<<<(N_NODES + 63) / 64, 256, 0, stream>>>(
        x, aggx, aggt, Gt, WSb, bias2, deg, out);
}

// Round 2
// 761.887 us; speedup vs baseline: 1.4092x; 1.4092x over previous
//
#include <hip/hip_runtime.h>

#define N_NODES 100000
#define N_EDGES 1000000
#define IN_CH   128
#define OUT_CH  128
#define T_DIM   64
#define K_TOT   320     // 128 (x) + 128 (agg_x) + 64 (agg_t)
#define NCHUNK  98      // ceil(100000/1024)

// ---------------------------------------------------------------------------
// Prep: build k-major weight matrix Gt[k][o] (k = 0..319) and bias2 = WTb+Tb
// ---------------------------------------------------------------------------
__global__ void prep_kernel(const float* __restrict__ WSw,
                            const float* __restrict__ WTw,
                            const float* __restrict__ Tw,
                            const float* __restrict__ WTb,
                            const float* __restrict__ Tb,
                            float* __restrict__ Gt,
                            float* __restrict__ bias2) {
    int idx = blockIdx.x * 256 + threadIdx.x;
    if (idx < K_TOT * 128) {
        int k = idx >> 7;
        int o = idx & 127;
        float v;
        if (k < 128)       v = WSw[o * 128 + k];
        else if (k < 256)  v = WTw[o * 128 + (k - 128)];
        else               v = Tw[o * 64 + (k - 256)];
        Gt[k * 128 + o] = v;
    }
    if (idx < 128) bias2[idx] = WTb[idx] + Tb[idx];
}

// ---------------------------------------------------------------------------
// CSR build: histogram -> scan -> fill perm
// ---------------------------------------------------------------------------
__global__ __launch_bounds__(256) void hist_kernel(const int* __restrict__ ei,
                                                   int* __restrict__ hist) {
    int e = blockIdx.x * 256 + threadIdx.x;
    if (e < N_EDGES) atomicAdd(&hist[ei[e]], 1);
}

__global__ __launch_bounds__(256) void scan_pass1(const int* __restrict__ hist,
                                                  int* __restrict__ chunksum) {
    __shared__ int ts[256];
    int b = blockIdx.x, t = threadIdx.x;
    int i = b * 1024 + t * 4;
    int s = 0;
#pragma unroll
    for (int j = 0; j < 4; ++j)
        if (i + j < N_NODES) s += hist[i + j];
    ts[t] = s;
    __syncthreads();
    for (int off = 128; off > 0; off >>= 1) {
        if (t < off) ts[t] += ts[t + off];
        __syncthreads();
    }
    if (t == 0) chunksum[b] = ts[0];
}

__global__ void scan_mid(const int* __restrict__ chunksum,
                         int* __restrict__ chunkoff) {
    if (threadIdx.x == 0 && blockIdx.x == 0) {
        int run = 0;
        for (int i = 0; i < NCHUNK; ++i) { chunkoff[i] = run; run += chunksum[i]; }
    }
}

__global__ __launch_bounds__(256) void scan_pass2(const int* __restrict__ hist,
                                                  const int* __restrict__ chunkoff,
                                                  int* __restrict__ offsets) {
    __shared__ int ts[256];
    int b = blockIdx.x, t = threadIdx.x;
    int i0 = b * 1024 + t * 4;
    int v[4];
    int s = 0;
#pragma unroll
    for (int j = 0; j < 4; ++j) {
        v[j] = (i0 + j < N_NODES) ? hist[i0 + j] : 0;
        s += v[j];
    }
    ts[t] = s;
    __syncthreads();
    // inclusive scan over 256 thread sums
    for (int off = 1; off < 256; off <<= 1) {
        int add = (t >= off) ? ts[t - off] : 0;
        __syncthreads();
        ts[t] += add;
        __syncthreads();
    }
    int run = chunkoff[b] + ts[t] - s;   // exclusive base for this thread
#pragma unroll
    for (int j = 0; j < 4; ++j) {
        if (i0 + j < N_NODES) offsets[i0 + j] = run;
        run += v[j];
    }
    if (b == 0 && t == 0) offsets[N_NODES] = N_EDGES;
}

__global__ __launch_bounds__(256) void fill_kernel(const int* __restrict__ ei,
                                                   int* __restrict__ cursor,
                                                   int* __restrict__ perm) {
    int e = blockIdx.x * 256 + threadIdx.x;
    if (e < N_EDGES) {
        int pos = atomicAdd(&cursor[ei[e]], 1);
        perm[pos] = e;
    }
}

// ---------------------------------------------------------------------------
// Segment reduce: one wave per node. Writes every output element exactly once
// (so no memsets needed): agg_x (into d_out), agg_t, deg.
// ---------------------------------------------------------------------------
__global__ __launch_bounds__(256) void agg_kernel(
        const float* __restrict__ x,
        const int*   __restrict__ ei,
        const float* __restrict__ tf,
        const int*   __restrict__ perm,
        const int*   __restrict__ offsets,
        float* __restrict__ aggx,
        float* __restrict__ aggt,
        float* __restrict__ deg) {
    int lane = threadIdx.x & 63;
    int n = blockIdx.x * 4 + (threadIdx.x >> 6);
    if (n >= N_NODES) return;

    int beg = offsets[n];
    int end = offsets[n + 1];

    float ax0 = 0.f, ax1 = 0.f, at = 0.f;

    int e_n = 0, col_n = 0;
    if (beg < end) { e_n = perm[beg]; col_n = ei[N_EDGES + e_n]; }
    for (int i = beg; i < end; ++i) {
        int e = e_n, col = col_n;
        if (i + 1 < end) {                 // prefetch next edge's indices
            e_n = perm[i + 1];
            col_n = ei[N_EDGES + e_n];
        }
        const float* xp = x + (size_t)col * 128;
        ax0 += xp[lane];
        ax1 += xp[64 + lane];
        at  += tf[(size_t)e * 64 + lane];
    }

    aggx[(size_t)n * 128 + lane]      = ax0;
    aggx[(size_t)n * 128 + 64 + lane] = ax1;
    aggt[(size_t)n * 64 + lane]       = at;
    if (lane == 0) deg[n] = (float)(end - beg);
}

// ---------------------------------------------------------------------------
// Node transform: out = relu([x | agg_x | agg_t] @ Gt + WSb + deg*bias2)
// Tiled SGEMM: 64 nodes x 128 outputs per block (256 threads),
// each thread computes 4 nodes x 8 outputs.
// NOTE: aggx aliases out (in-place) — deliberately NOT __restrict__.
// ---------------------------------------------------------------------------
__global__ __launch_bounds__(256) void gemm_kernel(
        const float* __restrict__ x,
        const float* aggx,
        const float* __restrict__ aggt,
        const float* __restrict__ Gt,
        const float* __restrict__ WSb,
        const float* __restrict__ bias2,
        const float* __restrict__ deg,
        float* out) {
    __shared__ float As[32][64];    // [kk][node]
    __shared__ float Bs[32][128];   // [kk][out]

    int tid = threadIdx.x;
    int tx = tid & 15;          // node group 0..15
    int ty = tid >> 4;          // out group  0..15
    int row0 = blockIdx.x * 64;

    float acc[4][8];
#pragma unroll
    for (int i = 0; i < 4; ++i)
#pragma unroll
        for (int j = 0; j < 8; ++j) acc[i][j] = 0.0f;

    int nn = tid >> 2;   // 0..63 : node for A staging
    int kq = tid & 3;    // 0..3  : 8-wide k slice for A staging
    int kr = tid >> 5;   // 0..7  : k row for B staging
    int o4 = (tid & 31) * 4;

    for (int c = 0; c < 10; ++c) {
        int kbase = c * 32;
        const float* src;
        int ld, koff;
        if (c < 4)      { src = x;    ld = 128; koff = kbase; }
        else if (c < 8) { src = aggx; ld = 128; koff = kbase - 128; }
        else            { src = aggt; ld = 64;  koff = kbase - 256; }

        int n = row0 + nn;
        float4 va = make_float4(0.f, 0.f, 0.f, 0.f);
        float4 vb = va;
        if (n < N_NODES) {
            const float* p = src + (size_t)n * ld + koff + kq * 8;
            va = *(const float4*)p;
            vb = *(const float4*)(p + 4);
        }

        __syncthreads();   // protect previous iteration's LDS reads

        int k0 = kq * 8;
        As[k0 + 0][nn] = va.x; As[k0 + 1][nn] = va.y;
        As[k0 + 2][nn] = va.z; As[k0 + 3][nn] = va.w;
        As[k0 + 4][nn] = vb.x; As[k0 + 5][nn] = vb.y;
        As[k0 + 6][nn] = vb.z; As[k0 + 7][nn] = vb.w;

#pragma unroll
        for (int r = 0; r < 4; ++r) {
            int kk = kr + r * 8;
            float4 b = *(const float4*)&Gt[(size_t)(kbase + kk) * 128 + o4];
            *(float4*)&Bs[kk][o4] = b;
        }

        __syncthreads();

#pragma unroll 8
        for (int kk = 0; kk < 32; ++kk) {
            float4 a4 = *(const float4*)&As[kk][tx * 4];
            float4 b0 = *(const float4*)&Bs[kk][ty * 8];
            float4 b1 = *(const float4*)&Bs[kk][ty * 8 + 4];
            float av[4] = {a4.x, a4.y, a4.z, a4.w};
            float bv[8] = {b0.x, b0.y, b0.z, b0.w, b1.x, b1.y, b1.z, b1.w};
#pragma unroll
            for (int i = 0; i < 4; ++i)
#pragma unroll
                for (int j = 0; j < 8; ++j)
                    acc[i][j] += av[i] * bv[j];
        }
    }

    // Epilogue: bias + deg*bias2 + ReLU. Safe to store in-place over aggx:
    // all global reads of this block's aggx rows happened during staging.
#pragma unroll
    for (int i = 0; i < 4; ++i) {
        int n = row0 + tx * 4 + i;
        if (n >= N_NODES) continue;
        float d = deg[n];
        float4 r0, r1;
        {
            int o = ty * 8;
            r0.x = fmaxf(acc[i][0] + WSb[o + 0] + d * bias2[o + 0], 0.f);
            r0.y = fmaxf(acc[i][1] + WSb[o + 1] + d * bias2[o + 1], 0.f);
            r0.z = fmaxf(acc[i][2] + WSb[o + 2] + d * bias2[o + 2], 0.f);
            r0.w = fmaxf(acc[i][3] + WSb[o + 3] + d * bias2[o + 3], 0.f);
            r1.x = fmaxf(acc[i][4] + WSb[o + 4] + d * bias2[o + 4], 0.f);
            r1.y = fmaxf(acc[i][5] + WSb[o + 5] + d * bias2[o + 5], 0.f);
            r1.z = fmaxf(acc[i][6] + WSb[o + 6] + d * bias2[o + 6], 0.f);
            r1.w = fmaxf(acc[i][7] + WSb[o + 7] + d * bias2[o + 7], 0.f);
        }
        float* po = out + (size_t)n * 128 + ty * 8;
        *(float4*)po = r0;
        *(float4*)(po + 4) = r1;
    }
}

// ---------------------------------------------------------------------------
extern "C" void kernel_launch(void* const* d_in, const int* in_sizes, int n_in,
                              void* d_out, int out_size, void* d_ws, size_t ws_size,
                              hipStream_t stream) {
    const float* x   = (const float*)d_in[0];
    const int*   ei  = (const int*)d_in[1];
    const float* tf  = (const float*)d_in[2];
    const float* WSw = (const float*)d_in[3];
    const float* WSb = (const float*)d_in[4];
    const float* WTw = (const float*)d_in[5];
    const float* WTb = (const float*)d_in[6];
    const float* Tw  = (const float*)d_in[7];
    const float* Tb  = (const float*)d_in[8];
    float* out = (float*)d_out;

    // Workspace layout:
    //   aggt   : N_NODES*64 f        (25.6 MB)
    //   deg    : N_NODES f
    //   Gt     : 320*128 f
    //   bias2  : 128 f
    //   hist   : N_NODES i
    //   offsets: N_NODES+1 i
    //   cursor : N_NODES i
    //   csum   : NCHUNK i
    //   coff   : NCHUNK i
    //   perm   : N_EDGES i           (4 MB)
    float* aggt  = (float*)d_ws;
    float* deg   = aggt + (size_t)N_NODES * 64;
    float* Gt    = deg + N_NODES;
    float* bias2 = Gt + (size_t)K_TOT * 128;
    int* hist    = (int*)(bias2 + 128);
    int* offsets = hist + N_NODES;
    int* cursor  = offsets + (N_NODES + 1);
    int* csum    = cursor + N_NODES;
    int* coff    = csum + NCHUNK;
    int* perm    = coff + NCHUNK;
    float* aggx  = out;   // reuse output buffer as agg_x accumulator

    hipMemsetAsync(hist, 0, (size_t)N_NODES * sizeof(int), stream);

    prep_kernel<<<(K_TOT * 128 + 255) / 256, 256, 0, stream>>>(
        WSw, WTw, Tw, WTb, Tb, Gt, bias2);

    hist_kernel<<<(N_EDGES + 255) / 256, 256, 0, stream>>>(ei, hist);
    scan_pass1<<<NCHUNK, 256, 0, stream>>>(hist, csum);
    scan_mid<<<1, 64, 0, stream>>>(csum, coff);
    scan_pass2<<<NCHUNK, 256, 0, stream>>>(hist, coff, offsets);

    hipMemcpyAsync(cursor, offsets, (size_t)N_NODES * sizeof(int),
                   hipMemcpyDeviceToDevice, stream);

    fill_kernel<<<(N_EDGES + 255) / 256, 256, 0, stream>>>(ei, cursor, perm);

    agg_kernel<<<(N_NODES + 3) / 4, 256, 0, stream>>>(
        x, ei, tf, perm, offsets, aggx, aggt, deg);

    gemm_kernel<<<(N_NODES + 63) / 64, 256, 0, stream>>>(
        x, aggx, aggt, Gt, WSb, bias2, deg, out);
}